// Round 1
// baseline (178.782 us; speedup 1.0000x reference)
//
#include <hip/hip_runtime.h>

// Problem constants (B,C,H,W)=(4,128,64,64), O=128, KS=7, PAD=3, GROUPS=8
constexpr int CI  = 128;   // input channels
constexpr int OQ  = 128;   // output channels of q/k/v
constexpr int HH  = 64, WW = 64;
constexpr int PHH = 70, PWW = 70;          // padded spatial
constexpr int HW4 = HH * WW;               // 4096
constexpr int QN  = 4 * HH * WW * OQ;      // q workspace floats  (2,097,152)
constexpr int KPN = 4 * PHH * PWW * OQ;    // padded k/v floats   (2,508,800)

// ---------------------------------------------------------------------------
// Kernel A: q/k/v 1x1-conv GEMMs.
//   q  -> channel-last unpadded  (b, h, w, c)
//   k,v-> channel-last PADDED    (b, y, x, c), pad region pre-zeroed by memset
// Each thread: 1 position, 8 output channels, all 3 matrices (24 accs).
// w accesses are block-uniform (o-group = blockIdx.y) -> scalar loads.
// ---------------------------------------------------------------------------
__global__ __launch_bounds__(256) void qkv_kernel(
    const float* __restrict__ x,
    const float* __restrict__ wq, const float* __restrict__ wk,
    const float* __restrict__ wv,
    float* __restrict__ qo, float* __restrict__ kp, float* __restrict__ vp)
{
    const int tid = threadIdx.x;
    const int pos = blockIdx.x * 256 + tid;      // 0..16383
    const int og  = blockIdx.y;                  // 0..15
    const int b   = pos >> 12;
    const int hw  = pos & 4095;
    const int h   = hw >> 6, w = hw & 63;
    const int o0  = og * 8;

    float aq[8], ak[8], av[8];
#pragma unroll
    for (int i = 0; i < 8; ++i) { aq[i] = 0.f; ak[i] = 0.f; av[i] = 0.f; }

    const float* xp = x + (size_t)b * CI * HW4 + hw;
#pragma unroll 4
    for (int c = 0; c < CI; ++c) {
        const float xv = xp[(size_t)c * HW4];
#pragma unroll
        for (int i = 0; i < 8; ++i) {
            aq[i] = fmaf(wq[(o0 + i) * CI + c], xv, aq[i]);
            ak[i] = fmaf(wk[(o0 + i) * CI + c], xv, ak[i]);
            av[i] = fmaf(wv[(o0 + i) * CI + c], xv, av[i]);
        }
    }

    float* qdst = qo + (size_t)pos * OQ + o0;
    const size_t pb = ((size_t)(b * PHH + h + 3) * PWW + (w + 3)) * OQ + o0;
#pragma unroll
    for (int i = 0; i < 8; ++i) qdst[i] = aq[i];
#pragma unroll
    for (int i = 0; i < 8; ++i) kp[pb + i] = ak[i];
#pragma unroll
    for (int i = 0; i < 8; ++i) vp[pb + i] = av[i];
}

// ---------------------------------------------------------------------------
// Kernel B: attention. One wave (64 lanes) per output pixel; 4 waves/block.
// Phase A: lane = neighbor (49 of 64 active; rest clamped) -> per-lane logit,
//          bias folded in from precomputed 16 group-sums, no reductions.
// Softmax: butterfly shfl_xor over the full wave.
// Phase B: lane = channel (c=lane, c+64) -> out, attn via LDS broadcast.
// Store:   transpose through LDS for 16B-chunk stores into (B,C,H,W).
// ---------------------------------------------------------------------------
__global__ __launch_bounds__(256) void attn_kernel(
    const float* __restrict__ qin, const float* __restrict__ kp,
    const float* __restrict__ vp,  const float* __restrict__ relx,
    const float* __restrict__ rely, float* __restrict__ out)
{
    __shared__ float qs[4][CI];      // per-wave q vector
    __shared__ float sxy[4][16];     // per-wave group sums (8 for x, 8 for y)
    __shared__ float attns[4][64];   // per-wave attention weights
    __shared__ float rels[112];      // rel_x (56) ++ rel_y (56)
    __shared__ float otile[4][CI];   // output transpose buffer

    const int tid  = threadIdx.x;
    const int wv   = tid >> 6;
    const int lane = tid & 63;
    const int pix  = blockIdx.x * 4 + wv;
    const int b    = pix >> 12;
    const int hw   = pix & 4095;
    const int h    = hw >> 6, w = hw & 63;

    if (tid < 112) rels[tid] = (tid < 56) ? relx[tid] : rely[tid - 56];
    qs[wv][lane]      = qin[(size_t)pix * OQ + lane];
    qs[wv][lane + 64] = qin[(size_t)pix * OQ + 64 + lane];
    __syncthreads();

    // group sums for relative-position bias: s_x[x] = sum_g q[g*16+x], etc.
    if (lane < 16) {
        float s = 0.f;
#pragma unroll
        for (int g = 0; g < 8; ++g) s += qs[wv][g * 16 + lane];
        sxy[wv][lane] = s;
    }
    __syncthreads();

    // ---- Phase A: logits, lane = neighbor ----
    const int n  = (lane < 49) ? lane : 48;   // clamp keeps loads in-bounds
    const int ki = n / 7, kj = n % 7;
    const float* krow =
        kp + ((size_t)(b * PHH + h + ki) * PWW + (w + kj)) * OQ;
    const float4* q4 = (const float4*)&qs[wv][0];
    const float4* k4 = (const float4*)krow;
    float acc = 0.f;
#pragma unroll 8
    for (int c4 = 0; c4 < CI / 4; ++c4) {
        const float4 qv = q4[c4];
        const float4 kv = k4[c4];
        acc = fmaf(qv.x, kv.x, acc);
        acc = fmaf(qv.y, kv.y, acc);
        acc = fmaf(qv.z, kv.z, acc);
        acc = fmaf(qv.w, kv.w, acc);
    }
    float bias = 0.f;
#pragma unroll
    for (int i = 0; i < 8; ++i) {
        bias = fmaf(sxy[wv][i],     rels[i * 7 + kj],      bias);  // bias_x[kj]
        bias = fmaf(sxy[wv][8 + i], rels[56 + i * 7 + ki], bias);  // bias_y[ki]
    }
    float logit = (lane < 49) ? (acc + bias) : -1e30f;

    // ---- softmax over the wave ----
    float m = logit;
#pragma unroll
    for (int off = 32; off; off >>= 1) m = fmaxf(m, __shfl_xor(m, off));
    const float e = __expf(logit - m);
    float s = e;
#pragma unroll
    for (int off = 32; off; off >>= 1) s += __shfl_xor(s, off);
    attns[wv][lane] = e / s;
    __syncthreads();

    // ---- Phase B: out, lane = channel ----
    float o0v = 0.f, o1v = 0.f;
    const float* vb = vp + ((size_t)(b * PHH + h) * PWW + w) * OQ + lane;
    int idx = 0;
    for (int ky = 0; ky < 7; ++ky) {
        const float* vr = vb + (size_t)ky * PWW * OQ;
#pragma unroll
        for (int kx = 0; kx < 7; ++kx) {
            const float a = attns[wv][idx++];
            o0v = fmaf(a, vr[kx * OQ], o0v);
            o1v = fmaf(a, vr[kx * OQ + 64], o1v);
        }
    }
    otile[wv][lane]      = o0v;
    otile[wv][lane + 64] = o1v;
    __syncthreads();

    // ---- cooperative transposed store into (B, C, H, W) ----
    const int pix0 = blockIdx.x * 4;
    const int b0   = pix0 >> 12;
    const int hw0  = pix0 & 4095;
#pragma unroll
    for (int it = 0; it < 2; ++it) {
        const int idx2 = it * 256 + tid;
        const int px   = idx2 & 3;
        const int c    = idx2 >> 2;
        out[((size_t)(b0 * OQ + c)) * HW4 + hw0 + px] = otile[px][c];
    }
}

extern "C" void kernel_launch(void* const* d_in, const int* in_sizes, int n_in,
                              void* d_out, int out_size, void* d_ws, size_t ws_size,
                              hipStream_t stream) {
    const float* x    = (const float*)d_in[0];
    const float* wq   = (const float*)d_in[1];
    const float* wk   = (const float*)d_in[2];
    const float* wv   = (const float*)d_in[3];
    const float* relx = (const float*)d_in[4];
    const float* rely = (const float*)d_in[5];
    float* out = (float*)d_out;

    float* qo = (float*)d_ws;          // 2,097,152 floats
    float* kpad = qo + QN;             // 2,508,800 floats (incl. zero pad)
    float* vpad = kpad + KPN;          // 2,508,800 floats (incl. zero pad)

    // zero the padded k/v buffers (pad region must be 0; ws is poisoned 0xAA)
    hipMemsetAsync(kpad, 0, (size_t)2 * KPN * sizeof(float), stream);

    qkv_kernel<<<dim3(64, 16), 256, 0, stream>>>(x, wq, wk, wv, qo, kpad, vpad);
    attn_kernel<<<dim3(4096), 256, 0, stream>>>(qo, kpad, vpad, relx, rely, out);
}

// Round 2
// 150.265 us; speedup vs baseline: 1.1898x; 1.1898x over previous
//
#include <hip/hip_runtime.h>

// Problem constants (B,C,H,W)=(4,128,64,64), O=128, KS=7, PAD=3, GROUPS=8
constexpr int CI  = 128;   // input channels
constexpr int OQ  = 128;   // output channels of q/k/v
constexpr int HH  = 64, WW = 64;
constexpr int PHH = 70, PWW = 70;          // padded spatial
constexpr int HW4 = HH * WW;               // 4096
constexpr int QN  = 4 * HH * WW * OQ;      // q workspace floats  (2,097,152)
constexpr int KPN = 4 * PHH * PWW * OQ;    // padded k/v floats   (2,508,800)

// ---------------------------------------------------------------------------
// Kernel A: q/k/v 1x1-conv as a register-blocked fp32 GEMM.
//   C[r][p], r in 0..383 (stacked q,k,v rows), p in 0..16383 (b*4096+hw), K=128.
//   Block tile: 64 r x 128 p. Thread: 8 r x 4 p = 32 accumulators.
//   Weights staged TRANSPOSED in LDS (Wt[c][o], pad 68 -> b128-aligned,
//   conflict-spread). X read from global, coalesced float4 per lane.
// ---------------------------------------------------------------------------
__global__ __launch_bounds__(256) void qkv_kernel(
    const float* __restrict__ x,
    const float* __restrict__ wq, const float* __restrict__ wk,
    const float* __restrict__ wv,
    float* __restrict__ qo, float* __restrict__ kp, float* __restrict__ vp)
{
    __shared__ float Wt[128][68];            // [c][r_local], padded

    const int tid = threadIdx.x;
    const int pt  = blockIdx.x;              // 0..127 position tile
    const int rt  = blockIdx.y;              // 0..5 row tile (matrix = rt>>1)
    const int m   = rt >> 1;
    const int o0  = (rt & 1) * 64;
    const float* wsrc = (m == 0) ? wq : (m == 1 ? wk : wv);

    // stage 64x128 weight tile, transposed, coalesced global reads
#pragma unroll
    for (int i = 0; i < 32; ++i) {
        const int idx = i * 256 + tid;       // 0..8191
        const int ol  = idx >> 7;            // 0..63
        const int c   = idx & 127;
        Wt[c][ol] = wsrc[(o0 + ol) * CI + c];
    }
    __syncthreads();

    const int tx = tid & 31;                 // p-quad
    const int ty = tid >> 5;                 // r-octet
    const int p0 = pt * 128 + tx * 4;        // 4 consecutive positions
    const int b  = p0 >> 12;
    const int hw = p0 & 4095;                // never crosses a row within +3

    float acc[8][4];
#pragma unroll
    for (int i = 0; i < 8; ++i)
#pragma unroll
        for (int j = 0; j < 4; ++j) acc[i][j] = 0.f;

    const float* xp = x + (size_t)b * CI * HW4 + hw;
    const float* wrow = &Wt[0][ty * 8];
#pragma unroll 4
    for (int c = 0; c < CI; ++c) {
        const float4 xv = *(const float4*)(xp + (size_t)c * HW4);
        const float4 w0 = *(const float4*)(wrow + c * 68);
        const float4 w1 = *(const float4*)(wrow + c * 68 + 4);
        const float wr[8] = {w0.x, w0.y, w0.z, w0.w, w1.x, w1.y, w1.z, w1.w};
#pragma unroll
        for (int i = 0; i < 8; ++i) {
            acc[i][0] = fmaf(wr[i], xv.x, acc[i][0]);
            acc[i][1] = fmaf(wr[i], xv.y, acc[i][1]);
            acc[i][2] = fmaf(wr[i], xv.z, acc[i][2]);
            acc[i][3] = fmaf(wr[i], xv.w, acc[i][3]);
        }
    }

    const int o_base = o0 + ty * 8;          // multiple of 8 -> 32B aligned
    if (m == 0) {
#pragma unroll
        for (int j = 0; j < 4; ++j) {
            float* dst = qo + (size_t)(p0 + j) * OQ + o_base;
            *(float4*)dst       = make_float4(acc[0][j], acc[1][j], acc[2][j], acc[3][j]);
            *(float4*)(dst + 4) = make_float4(acc[4][j], acc[5][j], acc[6][j], acc[7][j]);
        }
    } else {
        float* buf = (m == 1) ? kp : vp;
        const int h = hw >> 6, w = hw & 63;
#pragma unroll
        for (int j = 0; j < 4; ++j) {
            float* dst = buf + ((size_t)(b * PHH + h + 3) * PWW + (w + j + 3)) * OQ + o_base;
            *(float4*)dst       = make_float4(acc[0][j], acc[1][j], acc[2][j], acc[3][j]);
            *(float4*)(dst + 4) = make_float4(acc[4][j], acc[5][j], acc[6][j], acc[7][j]);
        }
    }
}

// ---------------------------------------------------------------------------
// Kernel B: attention, one wave per pixel, 4 waves/block.
// Phase A: lane = channel-pair (c=2*lane,2*lane+1) -> COALESCED float2 k loads;
//          49 per-lane partial logits; reduce 64->8 via 3 shfl_xor folds, then
//          8x49 LDS transpose finishes the sum on lanes 0..48.
// Softmax: butterfly over the wave. Phase B: lane = channel-pair, coalesced v.
// Store: transpose through LDS for contiguous stores into (B,C,H,W).
// ---------------------------------------------------------------------------
__global__ __launch_bounds__(256) void attn_kernel(
    const float* __restrict__ qin, const float* __restrict__ kp,
    const float* __restrict__ vp,  const float* __restrict__ relx,
    const float* __restrict__ rely, float* __restrict__ out)
{
    __shared__ float qs[4][CI];      // per-wave q vector
    __shared__ float sxy[4][16];     // per-wave group sums (8 x, 8 y)
    __shared__ float attns[4][64];   // per-wave attention weights
    __shared__ float rels[112];      // rel_x (56) ++ rel_y (56)
    __shared__ float tr[4][8][52];   // logit-reduction transpose buffer
    __shared__ float otile[4][CI];   // output transpose buffer

    const int tid  = threadIdx.x;
    const int wv   = tid >> 6;
    const int lane = tid & 63;
    const int pix  = blockIdx.x * 4 + wv;
    const int b    = pix >> 12;
    const int hw   = pix & 4095;
    const int h    = hw >> 6, w = hw & 63;

    if (tid < 112) rels[tid] = (tid < 56) ? relx[tid] : rely[tid - 56];
    const float2 q2 = ((const float2*)(qin + (size_t)pix * OQ))[lane];
    ((float2*)qs[wv])[lane] = q2;
    __syncthreads();

    // group sums for relative-position bias: s_x[t] = sum_g q[g*16+t], etc.
    if (lane < 16) {
        float s = 0.f;
#pragma unroll
        for (int g = 0; g < 8; ++g) s += qs[wv][g * 16 + lane];
        sxy[wv][lane] = s;
    }

    // ---- Phase A: per-lane partial logits, coalesced k loads ----
    float plog[49];
    const float* kbase = kp + ((size_t)(b * PHH + h) * PWW + w) * OQ;
    {
        int n = 0;
#pragma unroll
        for (int ki = 0; ki < 7; ++ki) {
            const float2* krow = (const float2*)(kbase + (size_t)ki * PWW * OQ);
#pragma unroll
            for (int kj = 0; kj < 7; ++kj) {
                const float2 k2 = krow[kj * 64 + lane];
                plog[n++] = q2.x * k2.x + q2.y * k2.y;
            }
        }
    }
    // fold 64 -> 8 lanes
#pragma unroll
    for (int n = 0; n < 49; ++n) {
        float v = plog[n];
        v += __shfl_xor(v, 1);
        v += __shfl_xor(v, 2);
        v += __shfl_xor(v, 4);
        plog[n] = v;
    }
    if ((lane & 7) == 0) {
        const int r = lane >> 3;
#pragma unroll
        for (int n = 0; n < 49; ++n) tr[wv][r][n] = plog[n];
    }
    __syncthreads();

    float logit = -1e30f;
    if (lane < 49) {
        float s = 0.f;
#pragma unroll
        for (int r = 0; r < 8; ++r) s += tr[wv][r][lane];
        const int ki = lane / 7, kj = lane % 7;
        float bias = 0.f;
#pragma unroll
        for (int i = 0; i < 8; ++i) {
            bias = fmaf(sxy[wv][i],     rels[i * 7 + kj],      bias);  // bias_x[kj]
            bias = fmaf(sxy[wv][8 + i], rels[56 + i * 7 + ki], bias);  // bias_y[ki]
        }
        logit = s + bias;
    }

    // ---- softmax over the wave ----
    float mx = logit;
#pragma unroll
    for (int off = 32; off; off >>= 1) mx = fmaxf(mx, __shfl_xor(mx, off));
    const float e = __expf(logit - mx);      // inactive lanes -> 0
    float ssum = e;
#pragma unroll
    for (int off = 32; off; off >>= 1) ssum += __shfl_xor(ssum, off);
    attns[wv][lane] = e / ssum;
    __syncthreads();

    // ---- Phase B: lane = channel-pair, coalesced v loads ----
    float2 o2 = make_float2(0.f, 0.f);
    const float* vbase = vp + ((size_t)(b * PHH + h) * PWW + w) * OQ;
    int idx = 0;
    for (int ki = 0; ki < 7; ++ki) {
        const float2* vrow = (const float2*)(vbase + (size_t)ki * PWW * OQ);
#pragma unroll
        for (int kj = 0; kj < 7; ++kj) {
            const float a = attns[wv][idx++];
            const float2 v2 = vrow[kj * 64 + lane];
            o2.x = fmaf(a, v2.x, o2.x);
            o2.y = fmaf(a, v2.y, o2.y);
        }
    }
    ((float2*)otile[wv])[lane] = o2;
    __syncthreads();

    // ---- cooperative transposed store into (B, C, H, W) ----
    const int pix0 = blockIdx.x * 4;
    const int b0   = pix0 >> 12;
    const int hw0  = pix0 & 4095;
#pragma unroll
    for (int it = 0; it < 2; ++it) {
        const int idx2 = it * 256 + tid;
        const int px   = idx2 & 3;
        const int c    = idx2 >> 2;
        out[((size_t)(b0 * OQ + c)) * HW4 + hw0 + px] = otile[px][c];
    }
}

extern "C" void kernel_launch(void* const* d_in, const int* in_sizes, int n_in,
                              void* d_out, int out_size, void* d_ws, size_t ws_size,
                              hipStream_t stream) {
    const float* x    = (const float*)d_in[0];
    const float* wq   = (const float*)d_in[1];
    const float* wk   = (const float*)d_in[2];
    const float* wv   = (const float*)d_in[3];
    const float* relx = (const float*)d_in[4];
    const float* rely = (const float*)d_in[5];
    float* out = (float*)d_out;

    float* qo   = (float*)d_ws;        // 2,097,152 floats
    float* kpad = qo + QN;             // 2,508,800 floats (incl. zero pad)
    float* vpad = kpad + KPN;          // 2,508,800 floats (incl. zero pad)

    // zero padded k/v buffers (pad region must be 0; ws is poisoned 0xAA)
    hipMemsetAsync(kpad, 0, (size_t)2 * KPN * sizeof(float), stream);

    qkv_kernel<<<dim3(128, 6), 256, 0, stream>>>(x, wq, wk, wv, qo, kpad, vpad);
    attn_kernel<<<dim3(4096), 256, 0, stream>>>(qo, kpad, vpad, relx, rely, out);
}

// Round 3
// 125.951 us; speedup vs baseline: 1.4195x; 1.1930x over previous
//
#include <hip/hip_runtime.h>

typedef __attribute__((ext_vector_type(8))) short short8;
typedef __attribute__((ext_vector_type(4))) float floatx4;

constexpr int CI = 128, OQ = 128, HH = 64, WW = 64, HW = 4096;

// ---- bf16 helpers (RNE) ----
__device__ __forceinline__ unsigned short f2bf(float f) {
    unsigned u = __float_as_uint(f);
    u += 0x7FFFu + ((u >> 16) & 1u);
    return (unsigned short)(u >> 16);
}
__device__ __forceinline__ float bf2f(unsigned short h) {
    return __uint_as_float(((unsigned)h) << 16);
}

// ---------------------------------------------------------------------------
// Kernel A: q/k/v 1x1-conv via bf16 MFMA with split-bf16 (hi/lo) 3-term
// product for fp32-class accuracy. out[o][p] = sum_c W[o][c] x[c][p].
// Wave: 2 o-tiles (A in regs, K=128) x 4 p-tiles of 16 px.
// Frags (16x16x32): A[m=L&15][k=quad*8+j], B[k=quad*8+j][n=L&15],
// D: col=L&15, row=quad*4+i  (guide §3, m89-verified).
// Outputs UNPADDED [p][c]; no memset needed anywhere.
// ---------------------------------------------------------------------------
__global__ __launch_bounds__(256, 3) void qkv_mfma(
    const float* __restrict__ x, const float* __restrict__ wq,
    const float* __restrict__ wk, const float* __restrict__ wv,
    float* __restrict__ qo, float* __restrict__ ko, float* __restrict__ vo)
{
    const int tid  = threadIdx.x;
    const int wvn  = tid >> 6, lane = tid & 63;
    const int g    = blockIdx.x;                 // 0..11 (o-group of 32 rows)
    const int mtx  = g >> 2;
    const float* wsrc = (mtx == 0) ? wq : (mtx == 1 ? wk : wv);
    float*       dst  = (mtx == 0) ? qo : (mtx == 1 ? ko : vo);
    const int olb  = (g & 3) * 32;               // local row base in matrix
    const int m    = lane & 15, quad = lane >> 4, kb = quad * 8;

    // A fragments: hi/lo split, held for both o-tiles, all 4 k-chunks
    short8 ahi[2][4], alo[2][4];
#pragma unroll
    for (int ot = 0; ot < 2; ++ot) {
#pragma unroll
        for (int ck = 0; ck < 4; ++ck) {
            const float* wrow = wsrc + (size_t)(olb + ot * 16 + m) * CI + ck * 32 + kb;
            const float4 w0 = *(const float4*)wrow;
            const float4 w1 = *(const float4*)(wrow + 4);
            const float f[8] = {w0.x, w0.y, w0.z, w0.w, w1.x, w1.y, w1.z, w1.w};
            short8 h, l;
#pragma unroll
            for (int j = 0; j < 8; ++j) {
                const unsigned short hb = f2bf(f[j]);
                h[j] = (short)hb;
                l[j] = (short)f2bf(f[j] - bf2f(hb));
            }
            ahi[ot][ck] = h; alo[ot][ck] = l;
        }
    }

    const int tile0 = blockIdx.y * 16 + wvn * 4;
    for (int t = 0; t < 4; ++t) {
        const int p0 = (tile0 + t) * 16;
        const int b  = p0 >> 12, hw = p0 & 4095;   // 16 px never cross h-row
        const float* xb = x + (size_t)b * (CI * HW) + hw + m;   // n = lane&15

        short8 bhi[4], blo[4];
#pragma unroll
        for (int ck = 0; ck < 4; ++ck) {
            float f[8];
#pragma unroll
            for (int j = 0; j < 8; ++j) f[j] = xb[(size_t)(ck * 32 + kb + j) * HW];
            short8 h, l;
#pragma unroll
            for (int j = 0; j < 8; ++j) {
                const unsigned short hb = f2bf(f[j]);
                h[j] = (short)hb;
                l[j] = (short)f2bf(f[j] - bf2f(hb));
            }
            bhi[ck] = h; blo[ck] = l;
        }

#pragma unroll
        for (int ot = 0; ot < 2; ++ot) {
            floatx4 acc = {0.f, 0.f, 0.f, 0.f};
#pragma unroll
            for (int ck = 0; ck < 4; ++ck)
                acc = __builtin_amdgcn_mfma_f32_16x16x32_bf16(alo[ot][ck], bhi[ck], acc, 0, 0, 0);
#pragma unroll
            for (int ck = 0; ck < 4; ++ck)
                acc = __builtin_amdgcn_mfma_f32_16x16x32_bf16(ahi[ot][ck], blo[ck], acc, 0, 0, 0);
#pragma unroll
            for (int ck = 0; ck < 4; ++ck)
                acc = __builtin_amdgcn_mfma_f32_16x16x32_bf16(ahi[ot][ck], bhi[ck], acc, 0, 0, 0);
            // store: p = p0 + col, o = olb + ot*16 + quad*4 + i
            float* d = dst + (size_t)(p0 + m) * OQ + olb + ot * 16 + quad * 4;
            *(floatx4*)d = acc;
        }
    }
}

// ---------------------------------------------------------------------------
// Kernel B: attention, LDS-tiled. Block = 512 thr = 8 waves = 8 pixels
// (one row segment, w0..w0+7). k/v halo (7 rows x 14 cols) staged once as
// packed-bf16 channel pairs, transposed [c2][pos] (stride 99 -> <=2-way
// banks). Out-of-range halo = zeros (replaces padding + memset).
// Phase A: lane=neighbor, serial LDS dot (no shuffles, no global scatter).
// Phase B: lane=channel-pair from LDS. Output via LDS transpose store.
// ---------------------------------------------------------------------------
constexpr int KST = 99;   // dword stride per c2 row (98 positions + 1 pad)

__global__ __launch_bounds__(512, 4) void attn_kernel(
    const float* __restrict__ qin, const float* __restrict__ kin,
    const float* __restrict__ vin, const float* __restrict__ relx,
    const float* __restrict__ rely, float* __restrict__ out)
{
    __shared__ unsigned k2[64 * KST];   // 25,344 B
    __shared__ unsigned v2[64 * KST];   // 25,344 B
    __shared__ float    qf[8 * 132];    //  4,224 B
    __shared__ float    attns[8][64];   //  2,048 B
    __shared__ float    sxy[8][16];     //    512 B
    __shared__ float    rels[112];      //    448 B
    __shared__ float    otile[8 * 132]; //  4,224 B   (total 62,144 B)

    const int tid = threadIdx.x;
    const int bx  = blockIdx.x;
    const int w0  = (bx & 7) * 8;
    const int h0  = (bx >> 3) & 63;
    const int b   = bx >> 9;
    const int rowbase = b * HW + h0 * WW;

    if (tid < 112) rels[tid] = (tid < 56) ? relx[tid] : rely[tid - 56];
    if (tid < 256) {                       // stage q (fp32), 8 px x 32 c4
        const int px = tid >> 5, c4 = tid & 31;
        const float4 qv = *(const float4*)(qin + (size_t)(rowbase + w0 + px) * CI + c4 * 4);
        *(float4*)&qf[px * 132 + c4 * 4] = qv;
    }
    // stage k/v halo: 98 positions x 32 c4-groups each, packed bf16 pairs
    for (int i = tid; i < 2 * 98 * 32; i += 512) {
        const int which = (i >= 3136);
        const int ii  = which ? i - 3136 : i;
        const int pos = ii >> 5, c4 = ii & 31;
        const int ri  = pos / 14, ci = pos - ri * 14;
        const int r   = h0 - 3 + ri, cw = w0 - 3 + ci;
        float4 t = make_float4(0.f, 0.f, 0.f, 0.f);
        if (r >= 0 && r < HH && cw >= 0 && cw < WW) {
            const float* src = which ? vin : kin;
            t = *(const float4*)(src + (size_t)(b * HW + r * WW + cw) * CI + c4 * 4);
        }
        unsigned* dstl = which ? v2 : k2;
        dstl[(2 * c4)     * KST + pos] = (unsigned)f2bf(t.x) | ((unsigned)f2bf(t.y) << 16);
        dstl[(2 * c4 + 1) * KST + pos] = (unsigned)f2bf(t.z) | ((unsigned)f2bf(t.w) << 16);
    }
    __syncthreads();

    const int wv = tid >> 6, lane = tid & 63;

    // group sums for relative-position bias
    if (lane < 16) {
        float s = 0.f;
#pragma unroll
        for (int gg = 0; gg < 8; ++gg) s += qf[wv * 132 + gg * 16 + lane];
        sxy[wv][lane] = s;
    }
    __syncthreads();

    // ---- Phase A: lane = neighbor, serial dot from LDS ----
    const int n  = (lane < 49) ? lane : 48;
    const int ki = n / 7, kj = n - ki * 7;
    const int pos = ki * 14 + wv + kj;
    float acc = 0.f;
#pragma unroll 8
    for (int c4 = 0; c4 < 32; ++c4) {
        const float4 qv = *(const float4*)&qf[wv * 132 + c4 * 4];
        const unsigned ka = k2[(2 * c4)     * KST + pos];
        const unsigned kb2 = k2[(2 * c4 + 1) * KST + pos];
        acc = fmaf(qv.x, __uint_as_float(ka << 16), acc);
        acc = fmaf(qv.y, __uint_as_float(ka & 0xFFFF0000u), acc);
        acc = fmaf(qv.z, __uint_as_float(kb2 << 16), acc);
        acc = fmaf(qv.w, __uint_as_float(kb2 & 0xFFFF0000u), acc);
    }
    float bias = 0.f;
#pragma unroll
    for (int i2 = 0; i2 < 8; ++i2) {
        bias = fmaf(sxy[wv][i2],     rels[i2 * 7 + kj],      bias);  // bias_x[kj]
        bias = fmaf(sxy[wv][8 + i2], rels[56 + i2 * 7 + ki], bias);  // bias_y[ki]
    }
    float logit = (lane < 49) ? acc + bias : -1e30f;

    // ---- softmax over the wave ----
    float mx = logit;
#pragma unroll
    for (int off = 32; off; off >>= 1) mx = fmaxf(mx, __shfl_xor(mx, off));
    const float e = __expf(logit - mx);
    float ssum = e;
#pragma unroll
    for (int off = 32; off; off >>= 1) ssum += __shfl_xor(ssum, off);
    attns[wv][lane] = e / ssum;
    __syncthreads();

    // ---- Phase B: lane = channel-pair (c = 2*lane, 2*lane+1) ----
    float olo = 0.f, ohi = 0.f;
#pragma unroll
    for (int nn = 0; nn < 49; ++nn) {
        const int kin2 = nn / 7, kjn = nn - kin2 * 7;
        const float a = attns[wv][nn];
        const unsigned vvb = v2[lane * KST + kin2 * 14 + wv + kjn];
        olo = fmaf(a, __uint_as_float(vvb << 16), olo);
        ohi = fmaf(a, __uint_as_float(vvb & 0xFFFF0000u), ohi);
    }
    otile[wv * 132 + 2 * lane]     = olo;
    otile[wv * 132 + 2 * lane + 1] = ohi;
    __syncthreads();

    // ---- cooperative transposed store into (B, C, H, W) ----
    for (int i = tid; i < 1024; i += 512) {
        const int c = i >> 3, pxw = i & 7;
        out[(size_t)(b * OQ + c) * HW + h0 * WW + w0 + pxw] = otile[pxw * 132 + c];
    }
}

extern "C" void kernel_launch(void* const* d_in, const int* in_sizes, int n_in,
                              void* d_out, int out_size, void* d_ws, size_t ws_size,
                              hipStream_t stream) {
    const float* x    = (const float*)d_in[0];
    const float* wq   = (const float*)d_in[1];
    const float* wk   = (const float*)d_in[2];
    const float* wv   = (const float*)d_in[3];
    const float* relx = (const float*)d_in[4];
    const float* rely = (const float*)d_in[5];
    float* out = (float*)d_out;

    float* qo = (float*)d_ws;                 // [16384][128] fp32, 8 MB
    float* ko = qo + (size_t)16384 * 128;     // 8 MB
    float* vo = ko + (size_t)16384 * 128;     // 8 MB

    qkv_mfma<<<dim3(12, 64), 256, 0, stream>>>(x, wq, wk, wv, qo, ko, vo);
    attn_kernel<<<dim3(2048), 512, 0, stream>>>(qo, ko, vo, relx, rely, out);
}

// Round 4
// 106.086 us; speedup vs baseline: 1.6853x; 1.1873x over previous
//
#include <hip/hip_runtime.h>

typedef __fp16 half8_t __attribute__((ext_vector_type(8)));
typedef __fp16 h2_t    __attribute__((ext_vector_type(2)));
typedef float  f4_t    __attribute__((ext_vector_type(4)));

constexpr int CI = 128, HW = 4096;

__device__ __forceinline__ h2_t u2h(unsigned u) { return __builtin_bit_cast(h2_t, u); }
__device__ __forceinline__ float dot2(unsigned k, unsigned q, float c) {
#if __has_builtin(__builtin_amdgcn_fdot2)
    return __builtin_amdgcn_fdot2(u2h(k), u2h(q), c, false);
#else
    h2_t kh = u2h(k), qh = u2h(q);
    return c + (float)kh[0] * (float)qh[0] + (float)kh[1] * (float)qh[1];
#endif
}

// ---------------------------------------------------------------------------
// Prepass: x -> f16 B-fragment planes; W (q,k,v) -> f16 A-fragment planes.
// B-frag file: ((t*4+ck)*64+lane)*8 halfs, lane=quad*16+n holds
//   x[b][c=ck*32+quad*8+j][hw=t*16+n].   (16 B/lane, 1 KB/wave coalesced)
// A-frag file: (((g*2+ot)*4+ck)*64+lane)*8 halfs, lane holds
//   w[olb+ot*16+(lane&15)][ck*32+(lane>>4)*8+j].
// ---------------------------------------------------------------------------
__global__ __launch_bounds__(256) void prepass(
    const float* __restrict__ x, const float* __restrict__ wq,
    const float* __restrict__ wk, const float* __restrict__ wv,
    __fp16* __restrict__ xh, __fp16* __restrict__ wh)
{
    const int tid = threadIdx.x, bx = blockIdx.x;
    const int wvn = tid >> 6, lane = tid & 63;
    const int quad = lane >> 4, n = lane & 15;
    if (bx < 1024) {
        const int t = bx, ck = wvn;
        const int p = t * 16 + n, b = p >> 12, hw = p & 4095;
        const float* src = x + (size_t)b * (CI * HW) + (size_t)(ck * 32 + quad * 8) * HW + hw;
        half8_t hv;
#pragma unroll
        for (int j = 0; j < 8; ++j) hv[j] = (__fp16)src[(size_t)j * HW];
        *(half8_t*)(xh + ((size_t)((t * 4 + ck) * 64 + lane)) * 8) = hv;
    } else {
        const int item = (bx - 1024) * 4 + wvn;        // 0..95 = ((g*2+ot)*4+ck)
        const int g = item >> 3, ot = (item >> 2) & 1, ck = item & 3;
        const int mtx = g >> 2, olb = (g & 3) * 32;
        const float* wsrc = (mtx == 0) ? wq : (mtx == 1 ? wk : wv);
        const float* row = wsrc + (size_t)(olb + ot * 16 + n) * CI + ck * 32 + quad * 8;
        half8_t hv;
#pragma unroll
        for (int j = 0; j < 8; ++j) hv[j] = (__fp16)row[j];
        *(half8_t*)(wh + ((size_t)(item * 64 + lane)) * 8) = hv;
    }
}

// ---------------------------------------------------------------------------
// QKV: f16 MFMA 16x16x32. Block=4 waves, wave: o-group g (32 rows), 4 px-tiles.
// Per tile: 4x 1KB coalesced frag loads + 8 MFMA. Epilogue: per-wave LDS
// transpose -> f16-packed global [pos][c2] (64 dwords/px), 64 B segments.
// D layout: col(px)=lane&15, row(o)=quad*4+i  (verified in round 3).
// ---------------------------------------------------------------------------
__global__ __launch_bounds__(256) void qkv_mfma(
    const __fp16* __restrict__ xh, const __fp16* __restrict__ wh,
    unsigned* __restrict__ qf, unsigned* __restrict__ kf, unsigned* __restrict__ vf)
{
    __shared__ float tlds[4][16 * 17];
    const int tid = threadIdx.x, wvn = tid >> 6, lane = tid & 63;
    const int g = blockIdx.x;
    const int m = lane & 15, quad = lane >> 4;
    unsigned* dst = (g < 4) ? qf : (g < 8 ? kf : vf);
    const int c2base = (g & 3) * 16;

    half8_t A[2][4];
#pragma unroll
    for (int ot = 0; ot < 2; ++ot)
#pragma unroll
        for (int ck = 0; ck < 4; ++ck)
            A[ot][ck] = *(const half8_t*)(wh + ((size_t)((((g * 2 + ot) * 4 + ck) * 64 + lane)) * 8));

    float* tl = tlds[wvn];
    const int t0 = blockIdx.y * 16 + wvn * 4;
    for (int ti = 0; ti < 4; ++ti) {
        const int t = t0 + ti;
        half8_t B[4];
#pragma unroll
        for (int ck = 0; ck < 4; ++ck)
            B[ck] = *(const half8_t*)(xh + ((size_t)((t * 4 + ck) * 64 + lane)) * 8);
        const int p0 = t * 16;
#pragma unroll
        for (int ot = 0; ot < 2; ++ot) {
            f4_t acc = {0.f, 0.f, 0.f, 0.f};
#pragma unroll
            for (int ck = 0; ck < 4; ++ck)
                acc = __builtin_amdgcn_mfma_f32_16x16x32_f16(A[ot][ck], B[ck], acc, 0, 0, 0);
            const int c2l = ot * 8 + quad * 2;
            tl[m * 17 + c2l]     = __builtin_bit_cast(float, __builtin_amdgcn_cvt_pkrtz(acc[0], acc[1]));
            tl[m * 17 + c2l + 1] = __builtin_bit_cast(float, __builtin_amdgcn_cvt_pkrtz(acc[2], acc[3]));
        }
        __asm__ volatile("s_waitcnt lgkmcnt(0)" ::: "memory");   // per-wave LDS transpose
        __builtin_amdgcn_wave_barrier();
#pragma unroll
        for (int s = 0; s < 4; ++s) {
            const int px = s * 4 + quad, c2l = m;
            dst[(size_t)(p0 + px) * 64 + c2base + c2l] =
                __builtin_bit_cast(unsigned, tl[px * 17 + c2l]);
        }
        __builtin_amdgcn_wave_barrier();
    }
}

// ---------------------------------------------------------------------------
// Attention: block = 512 thr = 8 waves = 16 px (2 rows x 8 cols). Wave owns a
// horizontal px pair. k/v halo (8x14 pos, f16 dwords) staged raw into LDS
// [c2][pos] pitch 114. Phase A: lane=neighbor, v_dot2_f32_f16 over 64 c2,
// q via wave-uniform loads. Phase B: lane=c2, attn broadcast via readlane,
// ds_read2 pair covers both px, v_pk f16 accumulate. otile aliases kS.
// ---------------------------------------------------------------------------
__global__ __launch_bounds__(512) void attn_kernel(
    const unsigned* __restrict__ qf, const unsigned* __restrict__ kf,
    const unsigned* __restrict__ vf, const float* __restrict__ relx,
    const float* __restrict__ rely, float* __restrict__ out)
{
    __shared__ unsigned smem[15232];                // 60,928 B
    unsigned* kS   = smem;                          // [64][114] = 7296
    unsigned* vS   = smem + 7296;                   // 7296
    float*    rels = (float*)(smem + 14592);        // 112
    float*    sxyL = (float*)(smem + 14704);        // 16*17
    float*    biasL= (float*)(smem + 14976);        // 16*16
    float*    otile= (float*)smem;                  // alias kS: 16*130 fp32

    const int tid = threadIdx.x, bx = blockIdx.x;
    const int wv = tid >> 6, lane = tid & 63;
    const int w0 = (bx & 7) * 8;
    const int h0 = ((bx >> 3) & 31) * 2;
    const int b  = bx >> 8;
    const int dr = wv >> 2, dw0 = (wv & 3) * 2;
    const int pixbase = b * 4096 + (h0 + dr) * 64 + (w0 + dw0);

    if (tid < 112) rels[tid] = (tid < 56) ? relx[tid] : rely[tid - 56];

    // ---- stage k/v halo: 2 x 112 pos x 32 c2-pairs (raw f16 dwords) ----
#pragma unroll
    for (int it = 0; it < 14; ++it) {
        int idx = it * 512 + tid;
        const int isv = idx >= 3584;
        idx -= isv * 3584;
        const int pos = idx >> 5, c2 = (idx & 31) * 2;
        const int ri = pos / 14, ci = pos - ri * 14;
        const int r = h0 - 3 + ri, cw = w0 - 3 + ci;
        uint2 d = make_uint2(0u, 0u);
        if ((unsigned)r < 64u && (unsigned)cw < 64u) {
            const unsigned* src = isv ? vf : kf;
            d = *(const uint2*)(src + (size_t)((b * 4096 + r * 64 + cw) * 64 + c2));
        }
        unsigned* dstS = isv ? vS : kS;
        dstS[c2 * 114 + pos]       = d.x;
        dstS[(c2 + 1) * 114 + pos] = d.y;
    }

    // ---- per-px group sums for relative bias (lanes 0..31 of each wave) ----
    if (lane < 32) {
        const int px01 = lane >> 4, t = lane & 15;
        const int pix = pixbase + px01;
        float s = 0.f;
#pragma unroll
        for (int gg = 0; gg < 8; ++gg) {
            const h2_t hh = u2h(qf[(size_t)pix * 64 + gg * 8 + (t >> 1)]);
            s += (float)hh[t & 1];
        }
        sxyL[(wv * 2 + px01) * 17 + t] = s;
    }
    __syncthreads();

    // ---- bias tables: biasL[wpx][kj] (x) and biasL[wpx][7+ki] (y) ----
    if (lane < 28) {
        const int px01 = lane >= 14;
        const int j = lane - px01 * 14;
        const int isy = j >= 7;
        const int jj = j - isy * 7;
        const float* sx = &sxyL[(wv * 2 + px01) * 17 + isy * 8];
        const float* rl = &rels[isy * 56 + jj];
        float s = 0.f;
#pragma unroll
        for (int i = 0; i < 8; ++i) s += sx[i] * rl[i * 7];
        biasL[(wv * 2 + px01) * 16 + j] = s;
    }
    __syncthreads();

    // ---- Phase A: logits + softmax per px (lane = neighbor) ----
    const int nn = (lane < 49) ? lane : 48;
    const int ki = (nn * 37) >> 8, kj = nn - ki * 7;
    int apk[2];
#pragma unroll
    for (int px01 = 0; px01 < 2; ++px01) {
        const int pixu = __builtin_amdgcn_readfirstlane(pixbase + px01);
        const uint4* qp = (const uint4*)(qf + (size_t)pixu * 64);
        const int pos = (dr + ki) * 14 + (dw0 + px01 + kj);
        float acc = 0.f;
#pragma unroll
        for (int c4 = 0; c4 < 16; ++c4) {
            const uint4 qw = qp[c4];
            acc = dot2(kS[(c4 * 4 + 0) * 114 + pos], qw.x, acc);
            acc = dot2(kS[(c4 * 4 + 1) * 114 + pos], qw.y, acc);
            acc = dot2(kS[(c4 * 4 + 2) * 114 + pos], qw.z, acc);
            acc = dot2(kS[(c4 * 4 + 3) * 114 + pos], qw.w, acc);
        }
        const float* bb = &biasL[(wv * 2 + px01) * 16];
        float logit = (lane < 49) ? acc + bb[kj] + bb[7 + ki] : -1e30f;
        float mx = logit;
#pragma unroll
        for (int off = 32; off; off >>= 1) mx = fmaxf(mx, __shfl_xor(mx, off));
        const float e = __expf(logit - mx);
        float ss = e;
#pragma unroll
        for (int off = 32; off; off >>= 1) ss += __shfl_xor(ss, off);
        const float a = e / ss;
        apk[px01] = __builtin_bit_cast(int, __builtin_amdgcn_cvt_pkrtz(a, a));
    }
    __syncthreads();   // all waves done reading kS before otile (alias) writes

    // ---- Phase B: lane = c2 (channels 2L, 2L+1); both px per ds_read pair ----
    const int posb = dr * 14 + dw0;
    h2_t o0 = {(__fp16)0.f, (__fp16)0.f}, o1 = o0;
#pragma unroll
    for (int n = 0; n < 49; ++n) {
        const int nki = (n * 37) >> 8, nkj = n - nki * 7;
        const int p = posb + nki * 14 + nkj;
        const unsigned va = vS[lane * 114 + p];        // px0's neighbor n
        const unsigned vb = vS[lane * 114 + p + 1];    // px1's neighbor n
        const h2_t a0 = u2h((unsigned)__builtin_amdgcn_readlane(apk[0], n));
        const h2_t a1 = u2h((unsigned)__builtin_amdgcn_readlane(apk[1], n));
        o0 += a0 * u2h(va);
        o1 += a1 * u2h(vb);
    }
    const int pxl0 = dr * 8 + dw0;
    {
        float2 f0 = make_float2((float)o0[0], (float)o0[1]);
        float2 f1 = make_float2((float)o1[0], (float)o1[1]);
        *(float2*)&otile[(size_t)pxl0 * 130 + lane * 2]       = f0;
        *(float2*)&otile[(size_t)(pxl0 + 1) * 130 + lane * 2] = f1;
    }
    __syncthreads();

    // ---- cooperative transposed store into (B, C, H, W) ----
#pragma unroll
    for (int s = 0; s < 4; ++s) {
        const int i = s * 512 + tid;
        const int c = i >> 4, pxl = i & 15;
        const int drr = pxl >> 3, dww = pxl & 7;
        out[(size_t)(b * 128 + c) * 4096 + (h0 + drr) * 64 + (w0 + dww)] =
            otile[pxl * 130 + c];
    }
}

extern "C" void kernel_launch(void* const* d_in, const int* in_sizes, int n_in,
                              void* d_out, int out_size, void* d_ws, size_t ws_size,
                              hipStream_t stream) {
    const float* x    = (const float*)d_in[0];
    const float* wq   = (const float*)d_in[1];
    const float* wk   = (const float*)d_in[2];
    const float* wv   = (const float*)d_in[3];
    const float* relx = (const float*)d_in[4];
    const float* rely = (const float*)d_in[5];
    float* out = (float*)d_out;

    char* ws = (char*)d_ws;
    __fp16*   xh = (__fp16*)(ws);                    // 4 MB  (f16 B-frags)
    __fp16*   wh = (__fp16*)(ws + 0x400000);         // 96 KB (f16 A-frags)
    unsigned* qf = (unsigned*)(ws + 0x420000);       // 4 MB  f16-packed [pos][c2]
    unsigned* kf = (unsigned*)(ws + 0x820000);       // 4 MB
    unsigned* vf = (unsigned*)(ws + 0xC20000);       // 4 MB

    prepass<<<dim3(1048), 256, 0, stream>>>(x, wq, wk, wv, xh, wh);
    qkv_mfma<<<dim3(12, 64), 256, 0, stream>>>(xh, wh, qf, kf, vf);
    attn_kernel<<<dim3(1024), 512, 0, stream>>>(qf, kf, vf, relx, rely, out);
}

// Round 5
// 103.296 us; speedup vs baseline: 1.7308x; 1.0270x over previous
//
#include <hip/hip_runtime.h>

typedef __fp16 half8_t __attribute__((ext_vector_type(8)));
typedef __fp16 h2_t    __attribute__((ext_vector_type(2)));
typedef float  f4_t    __attribute__((ext_vector_type(4)));

__device__ __forceinline__ h2_t u2h(unsigned u) { return __builtin_bit_cast(h2_t, u); }
__device__ __forceinline__ float dot2(unsigned k, unsigned q, float c) {
#if __has_builtin(__builtin_amdgcn_fdot2)
    return __builtin_amdgcn_fdot2(u2h(k), u2h(q), c, false);
#else
    h2_t kh = u2h(k), qh = u2h(q);
    return c + (float)kh[0] * (float)qh[0] + (float)kh[1] * (float)qh[1];
#endif
}
__device__ __forceinline__ unsigned pk(float a, float b) {
    return __builtin_bit_cast(unsigned, __builtin_amdgcn_cvt_pkrtz(a, b));
}

// ---------------------------------------------------------------------------
// QKV fused: 1x1-conv via f16 MFMA, W converted fp32->f16 frag-order in LDS
// once per block (32 KB), x converted inline per wave. Grid 768 = 3 matrices
// x 256 tile-groups; block = 4 waves = 4 px-tiles of 16. Wave: 32 MFMA.
// Output f16-packed [pos][c2] (the format attn stages). D layout:
// col(px)=lane&15, row(o)=quad*4+i (verified rounds 3/4).
// ---------------------------------------------------------------------------
__global__ __launch_bounds__(256) void qkv_fused(
    const float* __restrict__ x, const float* __restrict__ wq,
    const float* __restrict__ wk, const float* __restrict__ wv,
    unsigned* __restrict__ qf, unsigned* __restrict__ kf,
    unsigned* __restrict__ vf)
{
    __shared__ __fp16 Af[2048 * 8];          // 32 KB, ((otile*4+ck)*64+lane)*8
    __shared__ float  tl4[4][16 * 17];       // per-wave transpose buffer

    const int tid = threadIdx.x, wvn = tid >> 6, lane = tid & 63;
    const int mtx = blockIdx.x >> 8;         // 0=q 1=k 2=v
    const int tg  = blockIdx.x & 255;
    const float* wsrc = (mtx == 0) ? wq : (mtx == 1 ? wk : wv);
    unsigned*    dst  = (mtx == 0) ? qf : (mtx == 1 ? kf : vf);

    // ---- stage this matrix's W (128x128) as f16 A-frags in LDS ----
#pragma unroll
    for (int s = 0; s < 8; ++s) {
        const int it = s * 256 + tid;        // ((otile*4+ck)*64+l)
        const int l = it & 63, ck = (it >> 6) & 3, ot = it >> 8;
        const float* wr = wsrc + (size_t)(ot * 16 + (l & 15)) * 128 + ck * 32 + (l >> 4) * 8;
        const float4 w0 = *(const float4*)wr;
        const float4 w1 = *(const float4*)(wr + 4);
        half8_t h;
        h[0] = (__fp16)w0.x; h[1] = (__fp16)w0.y; h[2] = (__fp16)w0.z; h[3] = (__fp16)w0.w;
        h[4] = (__fp16)w1.x; h[5] = (__fp16)w1.y; h[6] = (__fp16)w1.z; h[7] = (__fp16)w1.w;
        *(half8_t*)&Af[it * 8] = h;
    }

    // ---- B-frags: convert this wave's 16-px x-tile ----
    const int t = tg * 4 + wvn;              // 0..1023
    const int m = lane & 15, quad = lane >> 4;
    const int p0 = t * 16, b = p0 >> 12, hw = p0 & 4095;
    const float* xb = x + (size_t)b * (128 * 4096) + hw + m;
    half8_t B[4];
#pragma unroll
    for (int ck = 0; ck < 4; ++ck) {
        half8_t h;
#pragma unroll
        for (int j = 0; j < 8; ++j)
            h[j] = (__fp16)xb[(size_t)(ck * 32 + quad * 8 + j) * 4096];
        B[ck] = h;
    }
    __syncthreads();

    float* tl = tl4[wvn];
#pragma unroll
    for (int og = 0; og < 4; ++og) {         // pairs of o-tiles (32 rows)
#pragma unroll
        for (int ot = 0; ot < 2; ++ot) {
            const int otile = og * 2 + ot;
            f4_t acc = {0.f, 0.f, 0.f, 0.f};
#pragma unroll
            for (int ck = 0; ck < 4; ++ck) {
                const half8_t A = *(const half8_t*)&Af[((otile * 4 + ck) * 64 + lane) * 8];
                acc = __builtin_amdgcn_mfma_f32_16x16x32_f16(A, B[ck], acc, 0, 0, 0);
            }
            const int c2l = ot * 8 + quad * 2;
            tl[m * 17 + c2l]     = __builtin_bit_cast(float, pk(acc[0], acc[1]));
            tl[m * 17 + c2l + 1] = __builtin_bit_cast(float, pk(acc[2], acc[3]));
        }
        __asm__ volatile("s_waitcnt lgkmcnt(0)" ::: "memory");
        __builtin_amdgcn_wave_barrier();
#pragma unroll
        for (int s = 0; s < 4; ++s) {
            const int px = s * 4 + quad;
            dst[(size_t)(p0 + px) * 64 + og * 16 + m] =
                __builtin_bit_cast(unsigned, tl[px * 17 + m]);
        }
        __builtin_amdgcn_wave_barrier();
    }
}

// ---------------------------------------------------------------------------
// Attention: block = 1024 thr = 16 waves = 32 px (4 rows x 8 cols); wave owns
// a horizontal px pair. k/v halo 10x14 pos staged raw (f16 dwords) into LDS
// [c2][pos] pitch 143 (odd -> 2-way banks, free). Phase A: lane=neighbor,
// ds_read2 serves both px, v_dot2_f32_f16, q via wave-uniform s_loads.
// Phase B: lane=c2, ds_read2 dual-px, attn broadcast via readlane, pk-f16 fma.
// 77.9 KB LDS -> 2 blocks/CU = 32 waves/CU (max occupancy).
// ---------------------------------------------------------------------------
__global__ __launch_bounds__(1024) void attn_kernel(
    const unsigned* __restrict__ qf, const unsigned* __restrict__ kf,
    const unsigned* __restrict__ vf, const float* __restrict__ relx,
    const float* __restrict__ rely, float* __restrict__ out)
{
    __shared__ unsigned smem[19472];                 // 77,888 B
    unsigned* kS    = smem;                          // [64][143]
    unsigned* vS    = smem + 9152;                   // [64][143]
    float*    rels  = (float*)(smem + 18304);        // 112
    float*    sxyL  = (float*)(smem + 18416);        // 32*17
    float*    biasL = (float*)(smem + 18960);        // 32*16
    float*    otile = (float*)smem;                  // alias kS: 32*130 fp32

    const int tid = threadIdx.x, bx = blockIdx.x;
    const int wv = tid >> 6, lane = tid & 63;
    const int w0 = (bx & 7) * 8;
    const int h0 = ((bx >> 3) & 15) * 4;
    const int b  = bx >> 7;
    const int dr = wv >> 2, dw0 = (wv & 3) * 2;      // wave's px pair

    if (tid < 112) rels[tid] = (tid < 56) ? relx[tid] : rely[tid - 56];

    // ---- stage k/v halo: 2 bufs x 140 pos x 32 uint2 (raw f16 dwords) ----
    for (int i = tid; i < 8960; i += 1024) {
        const int isv = i >= 4480;
        const int ii  = i - isv * 4480;
        const int pos = ii >> 5, c2 = (ii & 31) * 2;
        const int ri = pos / 14, ci = pos - ri * 14;
        const int r = h0 - 3 + ri, cw = w0 - 3 + ci;
        uint2 d = make_uint2(0u, 0u);
        if ((unsigned)r < 64u && (unsigned)cw < 64u) {
            const unsigned* src = isv ? vf : kf;
            d = *(const uint2*)(src + (size_t)((b * 4096 + r * 64 + cw) * 64 + c2));
        }
        unsigned* dstS = isv ? vS : kS;
        dstS[c2 * 143 + pos]       = d.x;
        dstS[(c2 + 1) * 143 + pos] = d.y;
    }

    // ---- per-px group sums for relative bias ----
    if (tid < 512) {
        const int px = tid >> 4, tt = tid & 15;
        const int pix = b * 4096 + (h0 + (px >> 3)) * 64 + w0 + (px & 7);
        float s = 0.f;
#pragma unroll
        for (int g = 0; g < 8; ++g) {
            const h2_t hh = u2h(qf[(size_t)pix * 64 + g * 8 + (tt >> 1)]);
            s += (float)hh[tt & 1];
        }
        sxyL[px * 17 + tt] = s;
    }
    __syncthreads();

    // ---- bias tables: biasL[px][kj] (x) and biasL[px][7+ki] (y) ----
    if (tid < 448) {
        const int px = tid / 14, j = tid - px * 14;
        const int isy = j >= 7, jj = j - isy * 7;
        const float* sx = &sxyL[px * 17 + isy * 8];
        const float* rl = &rels[isy * 56 + jj];
        float s = 0.f;
#pragma unroll
        for (int i = 0; i < 8; ++i) s = fmaf(sx[i], rl[i * 7], s);
        biasL[px * 16 + j] = s;
    }
    __syncthreads();

    // ---- Phase A: logits + softmax, lane = neighbor, dual-px LDS reads ----
    const int nn = (lane < 49) ? lane : 48;
    const int ki = (nn * 37) >> 8, kj = nn - ki * 7;
    const int pixu = __builtin_amdgcn_readfirstlane(
        b * 4096 + (h0 + dr) * 64 + (w0 + dw0));
    const uint4* qp0 = (const uint4*)(qf + (size_t)pixu * 64);
    const uint4* qp1 = (const uint4*)(qf + (size_t)(pixu + 1) * 64);
    const int pos = (dr + ki) * 14 + (dw0 + kj);
    float acc0 = 0.f, acc1 = 0.f;
#pragma unroll
    for (int c4 = 0; c4 < 16; ++c4) {
        const uint4 q0 = qp0[c4], q1 = qp1[c4];
        const unsigned* kb = &kS[(c4 * 4) * 143 + pos];
        unsigned lo, hi;
        lo = kb[0];       hi = kb[1];
        acc0 = dot2(lo, q0.x, acc0); acc1 = dot2(hi, q1.x, acc1);
        lo = kb[143];     hi = kb[144];
        acc0 = dot2(lo, q0.y, acc0); acc1 = dot2(hi, q1.y, acc1);
        lo = kb[286];     hi = kb[287];
        acc0 = dot2(lo, q0.z, acc0); acc1 = dot2(hi, q1.z, acc1);
        lo = kb[429];     hi = kb[430];
        acc0 = dot2(lo, q0.w, acc0); acc1 = dot2(hi, q1.w, acc1);
    }
    const int pxl0 = dr * 8 + dw0;
    int apk0, apk1;
    {
        const float* bb = &biasL[pxl0 * 16];
        float logit = (lane < 49) ? acc0 + bb[kj] + bb[7 + ki] : -1e30f;
        float mx = logit;
#pragma unroll
        for (int off = 32; off; off >>= 1) mx = fmaxf(mx, __shfl_xor(mx, off));
        const float e = __expf(logit - mx);
        float ss = e;
#pragma unroll
        for (int off = 32; off; off >>= 1) ss += __shfl_xor(ss, off);
        const float a = e / ss;
        apk0 = __builtin_bit_cast(int, __builtin_amdgcn_cvt_pkrtz(a, a));
    }
    {
        const float* bb = &biasL[(pxl0 + 1) * 16];
        float logit = (lane < 49) ? acc1 + bb[kj] + bb[7 + ki] : -1e30f;
        float mx = logit;
#pragma unroll
        for (int off = 32; off; off >>= 1) mx = fmaxf(mx, __shfl_xor(mx, off));
        const float e = __expf(logit - mx);
        float ss = e;
#pragma unroll
        for (int off = 32; off; off >>= 1) ss += __shfl_xor(ss, off);
        const float a = e / ss;
        apk1 = __builtin_bit_cast(int, __builtin_amdgcn_cvt_pkrtz(a, a));
    }
    __syncthreads();   // all waves done with kS before otile (alias) writes

    // ---- Phase B: lane = c2, dual-px ds_read2, readlane attn broadcast ----
    const int posb = dr * 14 + dw0;
    h2_t o0 = {(__fp16)0.f, (__fp16)0.f}, o1 = o0;
#pragma unroll
    for (int n = 0; n < 49; ++n) {
        const int nki = (n * 37) >> 8, nkj = n - nki * 7;
        const unsigned* vb = &vS[lane * 143 + posb + nki * 14 + nkj];
        const unsigned lo = vb[0], hi = vb[1];
        const h2_t a0 = u2h((unsigned)__builtin_amdgcn_readlane(apk0, n));
        const h2_t a1 = u2h((unsigned)__builtin_amdgcn_readlane(apk1, n));
        o0 += a0 * u2h(lo);
        o1 += a1 * u2h(hi);
    }
    *(float2*)&otile[(size_t)pxl0 * 130 + lane * 2] =
        make_float2((float)o0[0], (float)o0[1]);
    *(float2*)&otile[(size_t)(pxl0 + 1) * 130 + lane * 2] =
        make_float2((float)o1[0], (float)o1[1]);
    __syncthreads();

    // ---- cooperative transposed store into (B, C, H, W) ----
#pragma unroll
    for (int s = 0; s < 4; ++s) {
        const int i = s * 1024 + tid;
        const int pxl = i & 31, c = i >> 5;
        out[(size_t)(b * 128 + c) * 4096 + (h0 + (pxl >> 3)) * 64 + (w0 + (pxl & 7))] =
            otile[pxl * 130 + c];
    }
}

extern "C" void kernel_launch(void* const* d_in, const int* in_sizes, int n_in,
                              void* d_out, int out_size, void* d_ws, size_t ws_size,
                              hipStream_t stream) {
    const float* x    = (const float*)d_in[0];
    const float* wq   = (const float*)d_in[1];
    const float* wk   = (const float*)d_in[2];
    const float* wv   = (const float*)d_in[3];
    const float* relx = (const float*)d_in[4];
    const float* rely = (const float*)d_in[5];
    float* out = (float*)d_out;

    char* ws = (char*)d_ws;
    unsigned* qfb = (unsigned*)(ws);                 // 4 MB f16-packed [pos][c2]
    unsigned* kfb = (unsigned*)(ws + 0x400000);      // 4 MB
    unsigned* vfb = (unsigned*)(ws + 0x800000);      // 4 MB

    qkv_fused<<<dim3(768), 256, 0, stream>>>(x, wq, wk, wv, qfb, kfb, vfb);
    attn_kernel<<<dim3(512), 1024, 0, stream>>>(qfb, kfb, vfb, relx, rely, out);
}

// Round 6
// 97.409 us; speedup vs baseline: 1.8354x; 1.0604x over previous
//
#include <hip/hip_runtime.h>

typedef __fp16 half8_t __attribute__((ext_vector_type(8)));
typedef float  f4_t    __attribute__((ext_vector_type(4)));

__device__ __forceinline__ unsigned pk(float a, float b) {
    return __builtin_bit_cast(unsigned, __builtin_amdgcn_cvt_pkrtz(a, b));
}

// ---------------------------------------------------------------------------
// QKV fused: 1x1-conv via f16 MFMA (W f16 frag-order in LDS once per block,
// x converted inline). Grid 768 = 3 matrices x 256 groups; wave = 1 px-tile
// of 16, 32 MFMA. Output f16-packed [pos][c2]. Additionally, q-blocks
// precompute the relative-bias tables biasG[px][16] (j<7: bias_x[kj],
// 7..13: bias_y[ki]) from the per-px channel group-sums, which fall out of
// the D-fragments for free (lane's 4 acc elements all have t = c&15 =
// quad*4+e, g = c>>4 varying over the og/ot loop).
// ---------------------------------------------------------------------------
__global__ __launch_bounds__(256) void qkv_fused(
    const float* __restrict__ x, const float* __restrict__ wq,
    const float* __restrict__ wk, const float* __restrict__ wv,
    const float* __restrict__ relx, const float* __restrict__ rely,
    unsigned* __restrict__ qf, unsigned* __restrict__ kf,
    unsigned* __restrict__ vf, float* __restrict__ biasG)
{
    __shared__ __fp16 Af[2048 * 8];          // 32 KB A-frags
    __shared__ float  tl4[4][16 * 17];       // per-wave transpose buffer
    __shared__ float  sS[4][16 * 20];        // per-wave group sums [px][t]
    __shared__ float  relsQ[120];            // rel_x(56) ++ rel_y(56) ++ pad

    const int tid = threadIdx.x, wvn = tid >> 6, lane = tid & 63;
    const int mtx = blockIdx.x >> 8;         // 0=q 1=k 2=v
    const int tg  = blockIdx.x & 255;
    const float* wsrc = (mtx == 0) ? wq : (mtx == 1 ? wk : wv);
    unsigned*    dst  = (mtx == 0) ? qf : (mtx == 1 ? kf : vf);

    if (tid < 120)
        relsQ[tid] = (tid < 56) ? relx[tid] : (tid < 112 ? rely[tid - 56] : 0.f);

    // ---- stage W (128x128) as f16 A-frags ----
#pragma unroll
    for (int s = 0; s < 8; ++s) {
        const int it = s * 256 + tid;
        const int l = it & 63, ck = (it >> 6) & 3, ot = it >> 8;
        const float* wr = wsrc + (size_t)(ot * 16 + (l & 15)) * 128 + ck * 32 + (l >> 4) * 8;
        const float4 w0 = *(const float4*)wr;
        const float4 w1 = *(const float4*)(wr + 4);
        unsigned* d = (unsigned*)&Af[it * 8];
        d[0] = pk(w0.x, w0.y); d[1] = pk(w0.z, w0.w);
        d[2] = pk(w1.x, w1.y); d[3] = pk(w1.z, w1.w);
    }

    // ---- B-frags: this wave's 16-px x-tile ----
    const int t = tg * 4 + wvn;
    const int m = lane & 15, quad = lane >> 4;
    const int p0 = t * 16, b = p0 >> 12, hw = p0 & 4095;
    const float* xb = x + (size_t)b * (128 * 4096) + hw + m;
    half8_t B[4];
#pragma unroll
    for (int ck = 0; ck < 4; ++ck) {
        float f[8];
#pragma unroll
        for (int j = 0; j < 8; ++j) f[j] = xb[(size_t)(ck * 32 + quad * 8 + j) * 4096];
        unsigned* d = (unsigned*)&B[ck];
        d[0] = pk(f[0], f[1]); d[1] = pk(f[2], f[3]);
        d[2] = pk(f[4], f[5]); d[3] = pk(f[6], f[7]);
    }
    __syncthreads();

    float* tl = tl4[wvn];
    float s0 = 0.f, s1 = 0.f, s2 = 0.f, s3 = 0.f;   // group-sum partials
#pragma unroll
    for (int og = 0; og < 4; ++og) {
#pragma unroll
        for (int ot = 0; ot < 2; ++ot) {
            const int otile = og * 2 + ot;
            f4_t acc = {0.f, 0.f, 0.f, 0.f};
#pragma unroll
            for (int ck = 0; ck < 4; ++ck) {
                const half8_t A = *(const half8_t*)&Af[((otile * 4 + ck) * 64 + lane) * 8];
                acc = __builtin_amdgcn_mfma_f32_16x16x32_f16(A, B[ck], acc, 0, 0, 0);
            }
            if (mtx == 0) { s0 += acc[0]; s1 += acc[1]; s2 += acc[2]; s3 += acc[3]; }
            const int c2l = ot * 8 + quad * 2;
            tl[m * 17 + c2l]     = __builtin_bit_cast(float, pk(acc[0], acc[1]));
            tl[m * 17 + c2l + 1] = __builtin_bit_cast(float, pk(acc[2], acc[3]));
        }
        __asm__ volatile("s_waitcnt lgkmcnt(0)" ::: "memory");
        __builtin_amdgcn_wave_barrier();
#pragma unroll
        for (int s = 0; s < 4; ++s) {
            const int px = s * 4 + quad;
            dst[(size_t)(p0 + px) * 64 + og * 16 + m] =
                __builtin_bit_cast(unsigned, tl[px * 17 + m]);
        }
        __builtin_amdgcn_wave_barrier();
    }

    // ---- bias tables (q-blocks only): biasG[px][j] ----
    if (mtx == 0) {
        f4_t sv = {s0, s1, s2, s3};                     // t = quad*4 + e
        *(f4_t*)&sS[wvn][m * 20 + quad * 4] = sv;
        __asm__ volatile("s_waitcnt lgkmcnt(0)" ::: "memory");
        __builtin_amdgcn_wave_barrier();
        f4_t bj = {0.f, 0.f, 0.f, 0.f};
#pragma unroll
        for (int jj = 0; jj < 4; ++jj) {
            const int j = quad * 4 + jj;
            float s = 0.f;
            if (j < 7) {
#pragma unroll
                for (int tt = 0; tt < 8; ++tt)
                    s = fmaf(sS[wvn][m * 20 + tt], relsQ[tt * 7 + j], s);
            } else if (j < 14) {
#pragma unroll
                for (int tt = 0; tt < 8; ++tt)
                    s = fmaf(sS[wvn][m * 20 + 8 + tt], relsQ[56 + tt * 7 + (j - 7)], s);
            }
            bj[jj] = s;
        }
        *(f4_t*)(biasG + (size_t)(p0 + m) * 16 + quad * 4) = bj;
    }
}

// ---------------------------------------------------------------------------
// Attention, MFMA both phases. Block = 256 thr = 4 waves = 64 px (8x8).
// Wave owns 16 px (2 rows x 8 cols); its 112-pos halo window = 7 n-tiles.
// QK^T: Q/K B-frags DIRECT from global [pos][c2] (uint4/lane; OOB -> 0 ==
// reference zero-padding). Softmax in D-layout (mask ki,kj in [0,7), bias
// from biasG), weights -> per-wave aW[px][k] (A-frag layout, pad-shifted so
// ds_read_b128 stays 16B-aligned). PV: V^T staged once per block into
// vH[c][pos] via register v_perm transpose; 32 MFMA; fp32 D stored direct.
// LDS 77 KB. Total: 60 MFMA per 16 px.
// ---------------------------------------------------------------------------
__global__ __launch_bounds__(256) void attn_mfma(
    const unsigned* __restrict__ qf, const unsigned* __restrict__ kf,
    const unsigned* __restrict__ vf, const float* __restrict__ biasG,
    float* __restrict__ out)
{
    __shared__ __fp16 vH[128 * 216];         // 55,296 B  [c][halo pos 196+pad]
    __shared__ __fp16 aW[4 * 16 * 136];      // 17,408 B  per-wave weights
    __shared__ float  biasL[64 * 17];        //  4,352 B

    const int tid = threadIdx.x, bx = blockIdx.x;
    const int wv = tid >> 6, lane = tid & 63;
    const int n = lane & 15, quad = lane >> 4;
    const int w0 = (bx & 7) * 8, h0 = ((bx >> 3) & 7) * 8, b = bx >> 6;

    // ---- stage V halo transposed: 49 pos-quads x 32 c2-pairs ----
    for (int i = tid; i < 1568; i += 256) {
        const int pq = i >> 5, c2p = i & 31;
        const int pos0 = pq * 4;
        unsigned dx[4], dy[4];
#pragma unroll
        for (int p = 0; p < 4; ++p) {
            const int pos = pos0 + p;
            const int ri = (pos * 2341) >> 15;          // pos/14, pos<196
            const int ci = pos - ri * 14;
            const int py = h0 - 3 + ri, px = w0 - 3 + ci;
            uint2 d = make_uint2(0u, 0u);
            if ((unsigned)py < 64u && (unsigned)px < 64u)
                d = *(const uint2*)(vf + (size_t)((b * 4096 + py * 64 + px) * 64 + c2p * 2));
            dx[p] = d.x; dy[p] = d.y;
        }
        const int c0 = c2p * 4;
        *(uint2*)(vH + (c0 + 0) * 216 + pos0) = make_uint2(
            __builtin_amdgcn_perm(dx[1], dx[0], 0x05040100u),
            __builtin_amdgcn_perm(dx[3], dx[2], 0x05040100u));
        *(uint2*)(vH + (c0 + 1) * 216 + pos0) = make_uint2(
            __builtin_amdgcn_perm(dx[1], dx[0], 0x07060302u),
            __builtin_amdgcn_perm(dx[3], dx[2], 0x07060302u));
        *(uint2*)(vH + (c0 + 2) * 216 + pos0) = make_uint2(
            __builtin_amdgcn_perm(dy[1], dy[0], 0x05040100u),
            __builtin_amdgcn_perm(dy[3], dy[2], 0x05040100u));
        *(uint2*)(vH + (c0 + 3) * 216 + pos0) = make_uint2(
            __builtin_amdgcn_perm(dy[1], dy[0], 0x07060302u),
            __builtin_amdgcn_perm(dy[3], dy[2], 0x07060302u));
    }
    // zero pad tail pos 196..215 (128 rows x 5 uint2)
    for (int i = tid; i < 640; i += 256) {
        const int c = i / 5, s = i - c * 5;
        *(uint2*)(vH + c * 216 + 196 + s * 4) = make_uint2(0u, 0u);
    }
    // bias tables for this block's 64 px
    for (int i = tid; i < 1024; i += 256) {
        const int px = i >> 4, tt = i & 15;
        const int pix = b * 4096 + (h0 + (px >> 3)) * 64 + w0 + (px & 7);
        biasL[px * 17 + tt] = biasG[(size_t)pix * 16 + tt];
    }
    __syncthreads();

    // ---- Phase A: QK^T via MFMA (wave-local halo = rows 2wv..2wv+7) ----
    const int wrow = h0 + wv * 2;
    uint4 qA[4];
#pragma unroll
    for (int kc = 0; kc < 4; ++kc) {
        const int pix = b * 4096 + (wrow + (n >> 3)) * 64 + w0 + (n & 7);
        qA[kc] = *(const uint4*)(qf + (size_t)pix * 64 + kc * 16 + quad * 4);
    }
    f4_t lg[7];
#pragma unroll
    for (int t = 0; t < 7; ++t) {
        const int posL = t * 16 + n;                     // 0..111
        const int ri = (posL * 2341) >> 15;
        const int ci = posL - ri * 14;
        const int py = wrow - 3 + ri, pxc = w0 - 3 + ci;
        const bool val = ((unsigned)py < 64u) && ((unsigned)pxc < 64u);
        const int pix = b * 4096 + py * 64 + pxc;
        f4_t acc = {0.f, 0.f, 0.f, 0.f};
#pragma unroll
        for (int kc = 0; kc < 4; ++kc) {
            uint4 kB = make_uint4(0u, 0u, 0u, 0u);
            if (val) kB = *(const uint4*)(kf + (size_t)pix * 64 + kc * 16 + quad * 4);
            acc = __builtin_amdgcn_mfma_f32_16x16x32_f16(
                __builtin_bit_cast(half8_t, qA[kc]),
                __builtin_bit_cast(half8_t, kB), acc, 0, 0, 0);
        }
        lg[t] = acc;
    }

    // ---- mask + bias + per-px softmax (D-layout), weights -> aW ----
    const int pad = (wv & 1) * 4;                        // 16B-align shift
    {   // zero aW head/tail chunks (4 uint2 per px row)
        const int row = lane >> 2, ch = lane & 3;
        const int off = pad ? (ch == 0 ? 0 : 112 + pad + (ch - 1) * 4)
                            : 112 + ch * 4;
        *(uint2*)(aW + wv * 2176 + row * 136 + off) = make_uint2(0u, 0u);
    }
#pragma unroll
    for (int i = 0; i < 4; ++i) {
        const int px = quad * 4 + i;                     // wave-local px id
        const int dr = px >> 3, dw = px & 7;
        const float* bb = &biasL[(wv * 16 + px) * 17];
        float mx = -1e30f;
#pragma unroll
        for (int t = 0; t < 7; ++t) {
            const int posL = t * 16 + n;
            const int ri = (posL * 2341) >> 15;
            const int ci = posL - ri * 14;
            const unsigned ki = ri - dr, kj = ci - dw;
            float v = -1e30f;
            if (ki < 7u && kj < 7u) v = lg[t][i] + bb[kj] + bb[7 + ki];
            lg[t][i] = v;
            mx = fmaxf(mx, v);
        }
        mx = fmaxf(mx, __shfl_xor(mx, 1));
        mx = fmaxf(mx, __shfl_xor(mx, 2));
        mx = fmaxf(mx, __shfl_xor(mx, 4));
        mx = fmaxf(mx, __shfl_xor(mx, 8));
        float ss = 0.f;
#pragma unroll
        for (int t = 0; t < 7; ++t) {
            const float e = __expf(lg[t][i] - mx);
            lg[t][i] = e;
            ss += e;
        }
        ss += __shfl_xor(ss, 1);
        ss += __shfl_xor(ss, 2);
        ss += __shfl_xor(ss, 4);
        ss += __shfl_xor(ss, 8);
        const float inv = 1.f / ss;
#pragma unroll
        for (int t = 0; t < 7; ++t)
            aW[wv * 2176 + px * 136 + pad + t * 16 + n] = (__fp16)(lg[t][i] * inv);
    }
    __asm__ volatile("s_waitcnt lgkmcnt(0)" ::: "memory");
    __builtin_amdgcn_wave_barrier();

    // ---- Phase B: PV via MFMA, fp32 D stored direct to (B,C,H,W) ----
    const int startw = wv * 28 - pad;                    // {0,24,56,80}
    uint4 pA[4];
#pragma unroll
    for (int kc = 0; kc < 4; ++kc)
        pA[kc] = *(const uint4*)(aW + wv * 2176 + n * 136 + kc * 32 + quad * 8);
#pragma unroll
    for (int tn = 0; tn < 8; ++tn) {
        f4_t acc = {0.f, 0.f, 0.f, 0.f};
#pragma unroll
        for (int kc = 0; kc < 4; ++kc) {
            const half8_t vB = *(const half8_t*)(vH + (tn * 16 + n) * 216 +
                                                 startw + kc * 32 + quad * 8);
            acc = __builtin_amdgcn_mfma_f32_16x16x32_f16(
                __builtin_bit_cast(half8_t, pA[kc]), vB, acc, 0, 0, 0);
        }
        const int c = tn * 16 + n;
#pragma unroll
        for (int i = 0; i < 4; ++i) {
            const int px = quad * 4 + i;
            const int hwp = (wrow + (px >> 3)) * 64 + w0 + (px & 7);
            out[(size_t)(b * 128 + c) * 4096 + hwp] = acc[i];
        }
    }
}

extern "C" void kernel_launch(void* const* d_in, const int* in_sizes, int n_in,
                              void* d_out, int out_size, void* d_ws, size_t ws_size,
                              hipStream_t stream) {
    const float* x    = (const float*)d_in[0];
    const float* wq   = (const float*)d_in[1];
    const float* wk   = (const float*)d_in[2];
    const float* wv   = (const float*)d_in[3];
    const float* relx = (const float*)d_in[4];
    const float* rely = (const float*)d_in[5];
    float* out = (float*)d_out;

    char* ws = (char*)d_ws;
    unsigned* qfb = (unsigned*)(ws);                 // 4 MB f16-packed [pos][c2]
    unsigned* kfb = (unsigned*)(ws + 0x400000);      // 4 MB
    unsigned* vfb = (unsigned*)(ws + 0x800000);      // 4 MB
    float*    bG  = (float*)   (ws + 0xC00000);      // 1 MB bias tables

    qkv_fused<<<dim3(768), 256, 0, stream>>>(x, wq, wk, wv, relx, rely,
                                             qfb, kfb, vfb, bG);
    attn_mfma<<<dim3(256), 256, 0, stream>>>(qfb, kfb, vfb, bG, out);
}